// Round 18
// baseline (40.994 us; speedup 1.0000x reference)
//
#include <hip/hip_runtime.h>
#include <hip/hip_bf16.h>

// Problem constants
#define HSZ 32
#define HP1 33
#define M3 35937            // 33^3 (flattened j,k,l)
#define M3P 35952           // padded to multiple of 16 (2247*16)
#define TI_STRIDE 1149984   // 33^3 * 32 floats (stride of T over i)
#define TIB ((size_t)TI_STRIDE * 4)
#define NBLK 2247           // one wave per block
#define NT 64               // partial output tiles (contention 2247/64 ~ 35)
#define DEPTH 8             // LDS ring slots (rows in flight)

// ws layout (bytes): a0T @ 0 ; D @ 8192 ; tiles @ 4610048
#define OFF_A0T   0
#define OFF_D     8192
#define OFF_TILES 4610048

typedef short bf16x8 __attribute__((ext_vector_type(8)));
typedef float f32x16 __attribute__((ext_vector_type(16)));

__device__ inline short f2bf(float f) {
  __hip_bfloat16 h = __float2bfloat16(f);  // RTNE; pairs into v_cvt_pk_bf16_f32
  return __builtin_bit_cast(short, h);
}

// Prologue (r16 verbatim): D[b][m]=a1*a2*a3 (0 in pad), a0T[i][b], zero tiles.
__global__ __launch_bounds__(256) void k_pre(const float* __restrict__ nh,
                                             float* __restrict__ a0T,
                                             float* __restrict__ D,
                                             float* __restrict__ tiles) {
  const int b = blockIdx.y;
  const int m = blockIdx.x * 256 + threadIdx.x;
  if (m < M3P) {
    float v = 0.f;
    if (m < M3) {
      const int j = m / 1089;
      const int r = m - j * 1089;
      const int k = r / 33;
      const int l = r - k * 33;
      const float a1 = (j < HSZ) ? nh[(b * 4 + 1) * HSZ + j] : 1.0f;
      const float a2 = (k < HSZ) ? nh[(b * 4 + 2) * HSZ + k] : 1.0f;
      const float a3 = (l < HSZ) ? nh[(b * 4 + 3) * HSZ + l] : 1.0f;
      v = a1 * a2 * a3;
    }
    D[(size_t)b * M3P + m] = v;
  }
  if (blockIdx.x == 0 && threadIdx.x < HP1) {
    const int i = threadIdx.x;
    a0T[i * 32 + b] = (i < HSZ) ? nh[(b * 4 + 0) * HSZ + i] : 1.0f;
  }
  if (b == 1 && blockIdx.x < 64) {
    ((float4*)tiles)[blockIdx.x * 256 + threadIdx.x] =
        make_float4(0.f, 0.f, 0.f, 0.f);
  }
}

// Main: one wave per block; 8-slot LDS DMA ring (r16) + rotate-2 LDS->VGPR
// prefetch: ds_reads for row i+2 issued while computing row i, so the LDS
// latency hides under a full step instead of being exposed every step.
__global__ __launch_bounds__(64) void k_main(const float* __restrict__ T,
                                             const float* __restrict__ a0T,
                                             const float* __restrict__ D,
                                             float* __restrict__ tiles) {
  __shared__ float lds[DEPTH * 512];  // 8 slots x 2048 B
  const int blk = blockIdx.x;
  const int m0 = blk * 16;
  const int l = (int)threadIdx.x;  // 0..63
  const int bo = l & 31;           // A row (b) / B col (o)
  const int g = l >> 5;            // k-group: k = 8*g + e

  // A-side D fragment: D[bo][m0+8g+e]
  const float* dp = D + (size_t)bo * M3P + m0 + 8 * g;
  float df[8];
  *(float4*)(df)     = *(const float4*)(dp);
  *(float4*)(df + 4) = *(const float4*)(dp + 4);

  // a0 preload into registers
  float a0v[HP1];
#pragma unroll
  for (int i = 0; i < HP1; ++i) a0v[i] = a0T[i * 32 + bo];

  // Drain df/a0 loads BEFORE the DMA stream so vmcnt accounting stays pure.
  {
    float dsum = 0.f, asum = 0.f;
#pragma unroll
    for (int e = 0; e < 8; ++e) dsum += df[e];
#pragma unroll
    for (int i = 0; i < HP1; ++i) asum += a0v[i];
    asm volatile("" :: "v"(dsum), "v"(asum) : "memory");
  }

  // Per-lane DMA source byte offsets (16B/lane, 2 halves per row).
  const int mrel = l >> 3;
  const size_t src0 = (m0 + mrel < M3) ? ((size_t)(m0 * 32 + l * 4) * 4) : 0;
  const size_t src1 =
      (m0 + 8 + mrel < M3) ? ((size_t)(m0 * 32 + 256 + l * 4) * 4) : 0;
  const char* Tb = (const char*)T;

#define ISSUE(row_, slot_)                                                   \
  {                                                                          \
    const char* s0p_ = Tb + (size_t)(row_)*TIB + src0;                       \
    const char* s1p_ = Tb + (size_t)(row_)*TIB + src1;                       \
    __builtin_amdgcn_global_load_lds(                                        \
        (const __attribute__((address_space(1))) void*)s0p_,                 \
        (__attribute__((address_space(3))) void*)(&lds[(slot_)*512]),        \
        16, 0, 0);                                                           \
    __builtin_amdgcn_global_load_lds(                                        \
        (const __attribute__((address_space(1))) void*)s1p_,                 \
        (__attribute__((address_space(3))) void*)(&lds[(slot_)*512 + 256]),  \
        16, 0, 0);                                                           \
  }

  // Fill the ring: 16 DMA ops in flight.
  ISSUE(0, 0) ISSUE(1, 1) ISSUE(2, 2) ISSUE(3, 3)
  ISSUE(4, 4) ISSUE(5, 5) ISSUE(6, 6) ISSUE(7, 7)

  f32x16 acc = {};
  float R0[8], R1[8];  // rotate-2 register sets (even/odd steps)

#define LDSREAD(REGS_, slot_)                                     \
  {                                                               \
    _Pragma("unroll")                                             \
    for (int e = 0; e < 8; ++e)                                   \
      REGS_[e] = lds[(slot_) * 512 + (8 * g + e) * 32 + bo];      \
  }

  // Pre-loop: rows 0,1 landed (16-12=4 ops done >= rows 0,1); read them.
  asm volatile("s_waitcnt vmcnt(12)" ::: "memory");
  __builtin_amdgcn_sched_barrier(0);
  LDSREAD(R0, 0)
  LDSREAD(R1, 1)

  // Step i: compute row i from REGS_, refill slot i%8 with row i+8,
  // then (after vmcnt guarantees row i+2 landed) read slot (i+2)%8 into
  // the same register set for use at step i+2.
#define STEP(i_, REGS_, vm_, doIssue_, doPre_)                               \
  {                                                                          \
    bf16x8 af, bfr;                                                          \
    _Pragma("unroll")                                                        \
    for (int e = 0; e < 8; ++e) {                                            \
      af[e] = f2bf(a0v[i_] * df[e]);                                         \
      bfr[e] = f2bf(REGS_[e]);                                               \
    }                                                                        \
    acc = __builtin_amdgcn_mfma_f32_32x32x16_bf16(af, bfr, acc, 0, 0, 0);    \
    __builtin_amdgcn_sched_barrier(0);                                       \
    if (doIssue_) ISSUE((i_) + DEPTH, (i_) % DEPTH)                          \
    if (doPre_) {                                                            \
      asm volatile("s_waitcnt vmcnt(" #vm_ ")" ::: "memory");                \
      __builtin_amdgcn_sched_barrier(0);                                     \
      LDSREAD(REGS_, ((i_) + 2) % DEPTH)                                     \
    }                                                                        \
  }

  // 33 steps; steady vmcnt(12) while issuing (i<=24), drain 10..0 after.
  STEP(0,  R0, 12, 1, 1) STEP(1,  R1, 12, 1, 1) STEP(2,  R0, 12, 1, 1)
  STEP(3,  R1, 12, 1, 1) STEP(4,  R0, 12, 1, 1) STEP(5,  R1, 12, 1, 1)
  STEP(6,  R0, 12, 1, 1) STEP(7,  R1, 12, 1, 1) STEP(8,  R0, 12, 1, 1)
  STEP(9,  R1, 12, 1, 1) STEP(10, R0, 12, 1, 1) STEP(11, R1, 12, 1, 1)
  STEP(12, R0, 12, 1, 1) STEP(13, R1, 12, 1, 1) STEP(14, R0, 12, 1, 1)
  STEP(15, R1, 12, 1, 1) STEP(16, R0, 12, 1, 1) STEP(17, R1, 12, 1, 1)
  STEP(18, R0, 12, 1, 1) STEP(19, R1, 12, 1, 1) STEP(20, R0, 12, 1, 1)
  STEP(21, R1, 12, 1, 1) STEP(22, R0, 12, 1, 1) STEP(23, R1, 12, 1, 1)
  STEP(24, R0, 12, 1, 1) STEP(25, R1, 10, 0, 1) STEP(26, R0, 8, 0, 1)
  STEP(27, R1, 6, 0, 1)  STEP(28, R0, 4, 0, 1)  STEP(29, R1, 2, 0, 1)
  STEP(30, R0, 0, 0, 1)  STEP(31, R1, 0, 0, 0)  STEP(32, R0, 0, 0, 0)
#undef STEP
#undef LDSREAD
#undef ISSUE

  // Accumulate into one of NT partial tiles (r12 epilogue verbatim).
  // C/D layout (m74/m101): col=lane&31, row=(r&3)+8*(r>>2)+4*(lane>>5)
  float* tp = tiles + (size_t)(blk & (NT - 1)) * 1024;
#pragma unroll
  for (int r = 0; r < 16; ++r) {
    const int brow = (r & 3) + 8 * (r >> 2) + 4 * g;
    atomicAdd(tp + brow * 32 + bo, acc[r]);
  }
}

// Final reduce (r12 verbatim): out[idx] = sum over NT tiles.
__global__ __launch_bounds__(256) void k_red(const float* __restrict__ tiles,
                                             float* __restrict__ out) {
  const int idx = blockIdx.x * 256 + (int)threadIdx.x;
  float s = 0.f;
  for (int t = 0; t < NT; ++t) s += tiles[(size_t)t * 1024 + idx];
  out[idx] = s;
}

extern "C" void kernel_launch(void* const* d_in, const int* in_sizes, int n_in,
                              void* d_out, int out_size, void* d_ws, size_t ws_size,
                              hipStream_t stream) {
  const float* nh = (const float*)d_in[0];  // [32,4,32]
  const float* T  = (const float*)d_in[1];  // [33,33,33,33,32]
  float* out = (float*)d_out;               // [32,32] fp32
  char* ws = (char*)d_ws;
  float* a0T   = (float*)(ws + OFF_A0T);
  float* D     = (float*)(ws + OFF_D);
  float* tiles = (float*)(ws + OFF_TILES);

  k_pre<<<dim3(141, 32), 256, 0, stream>>>(nh, a0T, D, tiles);
  k_main<<<NBLK, 64, 0, stream>>>(T, a0T, D, tiles);
  k_red<<<4, 256, 0, stream>>>(tiles, out);
}

// Round 19
// 39.753 us; speedup vs baseline: 1.0312x; 1.0312x over previous
//
#include <hip/hip_runtime.h>
#include <hip/hip_bf16.h>

// Problem constants
#define HSZ 32
#define HP1 33
#define M3 35937            // 33^3 (flattened j,k,l)
#define M3P2 35968          // padded to 1124*32
#define TI_STRIDE 1149984   // 33^3 * 32 floats (stride of T over i)
#define TIB ((size_t)TI_STRIDE * 4)
#define NBLK 1124           // one wave per block, 32 m's per block
#define NT 64               // partial output tiles (contention 1124/64 ~ 18)
#define DEPTH 6             // LDS ring slots (rows in flight, 4KB each)

// ws layout (bytes): a0T @ 0 ; D @ 8192 (32*35968*4) ; tiles @ 4612096
#define OFF_A0T   0
#define OFF_D     8192
#define OFF_TILES 4612096

typedef short bf16x8 __attribute__((ext_vector_type(8)));
typedef float f32x16 __attribute__((ext_vector_type(16)));

__device__ inline short f2bf(float f) {
  __hip_bfloat16 h = __float2bfloat16(f);  // RTNE; pairs into v_cvt_pk_bf16_f32
  return __builtin_bit_cast(short, h);
}

// Prologue (r16 shape, pad to M3P2): D, a0T, zero tiles.
__global__ __launch_bounds__(256) void k_pre(const float* __restrict__ nh,
                                             float* __restrict__ a0T,
                                             float* __restrict__ D,
                                             float* __restrict__ tiles) {
  const int b = blockIdx.y;
  const int m = blockIdx.x * 256 + threadIdx.x;
  if (m < M3P2) {
    float v = 0.f;
    if (m < M3) {
      const int j = m / 1089;
      const int r = m - j * 1089;
      const int k = r / 33;
      const int l = r - k * 33;
      const float a1 = (j < HSZ) ? nh[(b * 4 + 1) * HSZ + j] : 1.0f;
      const float a2 = (k < HSZ) ? nh[(b * 4 + 2) * HSZ + k] : 1.0f;
      const float a3 = (l < HSZ) ? nh[(b * 4 + 3) * HSZ + l] : 1.0f;
      v = a1 * a2 * a3;
    }
    D[(size_t)b * M3P2 + m] = v;
  }
  if (blockIdx.x == 0 && threadIdx.x < HP1) {
    const int i = threadIdx.x;
    a0T[i * 32 + b] = (i < HSZ) ? nh[(b * 4 + 0) * HSZ + i] : 1.0f;
  }
  if (b == 1 && blockIdx.x < 64) {
    ((float4*)tiles)[blockIdx.x * 256 + threadIdx.x] =
        make_float4(0.f, 0.f, 0.f, 0.f);
  }
}

// Main: one wave per block; block owns 32 m's. 6-slot LDS DMA ring (4KB
// rows), counted vmcnt(20) steady state; 2 MFMAs per row into one acc.
__global__ __launch_bounds__(64) void k_main(const float* __restrict__ T,
                                             const float* __restrict__ a0T,
                                             const float* __restrict__ D,
                                             float* __restrict__ tiles) {
  __shared__ float lds[DEPTH * 1024];  // 6 slots x 4096 B
  const int blk = blockIdx.x;
  const int m0 = blk * 32;
  const int l = (int)threadIdx.x;  // 0..63
  const int bo = l & 31;           // A row (b) / B col (o)
  const int g = l >> 5;            // k-group: k = 8*g + e

  // A-side D fragments: half0 = D[bo][m0+8g+e], half1 = D[bo][m0+16+8g+e]
  const float* dp = D + (size_t)bo * M3P2 + m0 + 8 * g;
  float df0[8], df1[8];
  *(float4*)(df0)     = *(const float4*)(dp);
  *(float4*)(df0 + 4) = *(const float4*)(dp + 4);
  *(float4*)(df1)     = *(const float4*)(dp + 16);
  *(float4*)(df1 + 4) = *(const float4*)(dp + 20);

  // a0 preload into registers
  float a0v[HP1];
#pragma unroll
  for (int i = 0; i < HP1; ++i) a0v[i] = a0T[i * 32 + bo];

  // Drain prologue loads BEFORE the DMA stream (pure vmcnt accounting).
  {
    float s = 0.f;
#pragma unroll
    for (int e = 0; e < 8; ++e) s += df0[e] + df1[e];
#pragma unroll
    for (int i = 0; i < HP1; ++i) s += a0v[i];
    asm volatile("" :: "v"(s) : "memory");
  }

  // Per-lane DMA source byte offsets: op q covers row floats [q*256+4l, +4)
  // i.e. m-rel = 8q + (l>>3). Pad lanes clamp to 0 (values unused, df=0).
  const int mrel = l >> 3;
  size_t src[4];
#pragma unroll
  for (int q = 0; q < 4; ++q) {
    const bool valid = (m0 + 8 * q + mrel) < M3;
    src[q] = valid ? ((size_t)(m0 * 32 + q * 256 + l * 4) * 4) : 0;
  }
  const char* Tb = (const char*)T;

#define ISSUE(row_, slot_)                                                    \
  {                                                                           \
    _Pragma("unroll")                                                         \
    for (int q = 0; q < 4; ++q) {                                             \
      __builtin_amdgcn_global_load_lds(                                       \
          (const __attribute__((address_space(1))) void*)(                    \
              Tb + (size_t)(row_)*TIB + src[q]),                              \
          (__attribute__((address_space(3))) void*)(                          \
              &lds[(slot_)*1024 + q * 256]),                                  \
          16, 0, 0);                                                          \
    }                                                                         \
  }

  // Fill the ring: 24 DMA ops in flight.
  ISSUE(0, 0) ISSUE(1, 1) ISSUE(2, 2) ISSUE(3, 3) ISSUE(4, 4) ISSUE(5, 5)

  f32x16 acc = {};

#define STEP(i_, vm_, doIssue_)                                               \
  {                                                                           \
    asm volatile("s_waitcnt vmcnt(" #vm_ ")" ::: "memory");                   \
    __builtin_amdgcn_sched_barrier(0);                                        \
    float tv0[8], tv1[8];                                                     \
    _Pragma("unroll")                                                         \
    for (int e = 0; e < 8; ++e) {                                             \
      tv0[e] = lds[((i_) % DEPTH) * 1024 + (8 * g + e) * 32 + bo];            \
      tv1[e] = lds[((i_) % DEPTH) * 1024 + 512 + (8 * g + e) * 32 + bo];      \
    }                                                                         \
    asm volatile("s_waitcnt lgkmcnt(0)" ::: "memory");                        \
    if (doIssue_) ISSUE((i_) + DEPTH, (i_) % DEPTH)                           \
    bf16x8 af0, bf0, af1, bf1;                                                \
    _Pragma("unroll")                                                         \
    for (int e = 0; e < 8; ++e) {                                             \
      af0[e] = f2bf(a0v[i_] * df0[e]);                                        \
      bf0[e] = f2bf(tv0[e]);                                                  \
      af1[e] = f2bf(a0v[i_] * df1[e]);                                        \
      bf1[e] = f2bf(tv1[e]);                                                  \
    }                                                                         \
    acc = __builtin_amdgcn_mfma_f32_32x32x16_bf16(af0, bf0, acc, 0, 0, 0);    \
    acc = __builtin_amdgcn_mfma_f32_32x32x16_bf16(af1, bf1, acc, 0, 0, 0);    \
  }

  // 33 steps: steady vmcnt(20) while issuing (i<=26), then drain.
  STEP(0, 20, 1)  STEP(1, 20, 1)  STEP(2, 20, 1)  STEP(3, 20, 1)
  STEP(4, 20, 1)  STEP(5, 20, 1)  STEP(6, 20, 1)  STEP(7, 20, 1)
  STEP(8, 20, 1)  STEP(9, 20, 1)  STEP(10, 20, 1) STEP(11, 20, 1)
  STEP(12, 20, 1) STEP(13, 20, 1) STEP(14, 20, 1) STEP(15, 20, 1)
  STEP(16, 20, 1) STEP(17, 20, 1) STEP(18, 20, 1) STEP(19, 20, 1)
  STEP(20, 20, 1) STEP(21, 20, 1) STEP(22, 20, 1) STEP(23, 20, 1)
  STEP(24, 20, 1) STEP(25, 20, 1) STEP(26, 20, 1) STEP(27, 20, 0)
  STEP(28, 16, 0) STEP(29, 12, 0) STEP(30, 8, 0)  STEP(31, 4, 0)
  STEP(32, 0, 0)
#undef STEP
#undef ISSUE

  // Accumulate into one of NT partial tiles (r12 epilogue).
  // C/D layout (m74/m101): col=lane&31, row=(r&3)+8*(r>>2)+4*(lane>>5)
  float* tp = tiles + (size_t)(blk & (NT - 1)) * 1024;
#pragma unroll
  for (int r = 0; r < 16; ++r) {
    const int brow = (r & 3) + 8 * (r >> 2) + 4 * g;
    atomicAdd(tp + brow * 32 + bo, acc[r]);
  }
}

// Final reduce (r12 verbatim): out[idx] = sum over NT tiles.
__global__ __launch_bounds__(256) void k_red(const float* __restrict__ tiles,
                                             float* __restrict__ out) {
  const int idx = blockIdx.x * 256 + (int)threadIdx.x;
  float s = 0.f;
  for (int t = 0; t < NT; ++t) s += tiles[(size_t)t * 1024 + idx];
  out[idx] = s;
}

extern "C" void kernel_launch(void* const* d_in, const int* in_sizes, int n_in,
                              void* d_out, int out_size, void* d_ws, size_t ws_size,
                              hipStream_t stream) {
  const float* nh = (const float*)d_in[0];  // [32,4,32]
  const float* T  = (const float*)d_in[1];  // [33,33,33,33,32]
  float* out = (float*)d_out;               // [32,32] fp32
  char* ws = (char*)d_ws;
  float* a0T   = (float*)(ws + OFF_A0T);
  float* D     = (float*)(ws + OFF_D);
  float* tiles = (float*)(ws + OFF_TILES);

  k_pre<<<dim3(141, 32), 256, 0, stream>>>(nh, a0T, D, tiles);
  k_main<<<NBLK, 64, 0, stream>>>(T, a0T, D, tiles);
  k_red<<<4, 256, 0, stream>>>(tiles, out);
}